// Round 3
// baseline (1016.807 us; speedup 1.0000x reference)
//
#include <hip/hip_runtime.h>
#include <stdint.h>

// TransformerConv (heads=1) on gfx950. FP32 in/out.
//   alpha_e = scale * ( q[dst]·k[src] + t[dst]·ea_e ),  t_r = Σ_c We[r][c] q_c
//   out[i]  = ( Σ ex·v[src] + (Σ ex·ea) @ We ) / (Σ ex + 1e-16) + skip[i]
// CSR per call (hist / 3-phase scan / fill int2) -> wave-per-node gather with
// register-cached edge lists + 4-edge ILP. q,k,v,t staged bf16, fp32 accum.

__device__ __forceinline__ float b2f(uint16_t u) {
    union { uint32_t i; float f; } z; z.i = ((uint32_t)u) << 16; return z.f;
}
__device__ __forceinline__ uint16_t f2b(float f) {
    uint32_t u = __float_as_uint(f);
    uint32_t r = (u + 0x7FFFu + ((u >> 16) & 1u)) >> 16;
    return (uint16_t)r;
}

// ---------------- node kernel: 4 nodes/iter; q,k,v,skip (128->64), t = We@q ----
__global__ __launch_bounds__(256) void node_kernel(
    const float* __restrict__ x,
    const float* __restrict__ Wq, const float* __restrict__ bq,
    const float* __restrict__ Wk, const float* __restrict__ bk,
    const float* __restrict__ Wv, const float* __restrict__ bv,
    const float* __restrict__ We, const float* __restrict__ Wsk,
    const float* __restrict__ bsk,
    uint16_t* __restrict__ qb, uint16_t* __restrict__ kb, uint16_t* __restrict__ vb,
    uint16_t* __restrict__ tb, float* __restrict__ skipf, int n)
{
    __shared__ __align__(16) float xs[4 * 128];
    __shared__ float qs[4][64];
    __shared__ float WeT[64 * 65];             // WeT[j*65+c] = We[c*64+j], padded
    const int tid = threadIdx.x;
    const int c   = tid & 63;
    const int m   = tid >> 6;
    const float* Wsel = (m == 0) ? Wq : ((m == 1) ? Wk : ((m == 2) ? Wv : Wsk));
    const float* bsel = (m == 0) ? bq : ((m == 1) ? bk : ((m == 2) ? bv : bsk));

    float wcol[128];
    #pragma unroll
    for (int r = 0; r < 128; ++r) wcol[r] = Wsel[r * 64 + c];
    const float bias = bsel[c];

    #pragma unroll
    for (int k = 0; k < 16; ++k) {             // load We, store transposed
        int idx = tid + k * 256;               // idx = r*64 + j
        int r = idx >> 6, j = idx & 63;
        WeT[j * 65 + r] = We[idx];             // banks (65j+r)%32=(j+r)%32: clean
    }

    const int ngroups = (n + 3) >> 2;
    for (int g = blockIdx.x; g < ngroups; g += gridDim.x) {
        const int base = g << 2;
        __syncthreads();                        // xs/qs reuse guard
        if (base + 4 <= n) {
            ((float2*)xs)[tid] = ((const float2*)(x + (size_t)base * 128))[tid];
        } else {
            #pragma unroll
            for (int k = 0; k < 2; ++k) {
                int idx = tid * 2 + k;
                int nd = idx >> 7;
                xs[idx] = (base + nd < n) ? x[(size_t)base * 128 + idx] : 0.f;
            }
        }
        __syncthreads();

        float acc[4];
        #pragma unroll
        for (int nd = 0; nd < 4; ++nd) acc[nd] = bias;
        #pragma unroll
        for (int r4 = 0; r4 < 32; ++r4) {
            #pragma unroll
            for (int nd = 0; nd < 4; ++nd) {
                float4 xv = ((const float4*)(xs + nd * 128))[r4];  // LDS broadcast
                acc[nd] = fmaf(xv.x, wcol[4 * r4 + 0], acc[nd]);
                acc[nd] = fmaf(xv.y, wcol[4 * r4 + 1], acc[nd]);
                acc[nd] = fmaf(xv.z, wcol[4 * r4 + 2], acc[nd]);
                acc[nd] = fmaf(xv.w, wcol[4 * r4 + 3], acc[nd]);
            }
        }
        #pragma unroll
        for (int nd = 0; nd < 4; ++nd) {
            if (base + nd >= n) break;
            const size_t o64 = (size_t)(base + nd) * 64 + c;
            if (m == 0)      { qb[o64] = f2b(acc[nd]); qs[nd][c] = acc[nd]; }
            else if (m == 1) { kb[o64] = f2b(acc[nd]); }
            else if (m == 2) { vb[o64] = f2b(acc[nd]); }
            else             { skipf[o64] = acc[nd]; }
        }
        __syncthreads();
        if (base + m < n) {                    // wave m: t for node base+m
            float tacc = 0.f;
            #pragma unroll 8
            for (int j = 0; j < 64; ++j)
                tacc = fmaf(qs[m][j], WeT[j * 65 + c], tacc);
            tb[(size_t)(base + m) * 64 + c] = f2b(tacc);
        }
    }
}

// ---------------- CSR build ----------------
__global__ void hist_kernel(const int* __restrict__ dst, int* __restrict__ deg, int E) {
    int e = blockIdx.x * 256 + threadIdx.x;
    if (e < E) atomicAdd(&deg[dst[e]], 1);
}

#define SCAN_TILE 4096
__global__ __launch_bounds__(256) void scan_reduce_kernel(
    const int* __restrict__ deg, int* __restrict__ tsum, int n)
{
    __shared__ int ws[4];
    const int base = blockIdx.x * SCAN_TILE;
    const int tid  = threadIdx.x;
    int s = 0;
    #pragma unroll
    for (int k = 0; k < 16; ++k) {
        int idx = base + k * 256 + tid;
        if (idx < n) s += deg[idx];
    }
    #pragma unroll
    for (int d2 = 32; d2 >= 1; d2 >>= 1) s += __shfl_xor(s, d2, 64);
    if ((tid & 63) == 0) ws[tid >> 6] = s;
    __syncthreads();
    if (tid == 0) tsum[blockIdx.x] = ws[0] + ws[1] + ws[2] + ws[3];
}

__global__ __launch_bounds__(64) void scan_tsum_kernel(
    const int* __restrict__ tsum, int* __restrict__ texcl,
    int* __restrict__ offsets_n, int T)
{
    const int lane = threadIdx.x;
    int v = (lane < T) ? tsum[lane] : 0;
    int incl = v;
    #pragma unroll
    for (int off = 1; off < 64; off <<= 1) {
        int y = __shfl_up(incl, off, 64);
        if (lane >= off) incl += y;
    }
    if (lane < T) texcl[lane] = incl - v;
    if (lane == 63) *offsets_n = incl;         // total E
}

__global__ __launch_bounds__(256) void scan_apply_kernel(
    const int* __restrict__ deg, const int* __restrict__ texcl,
    int* __restrict__ offsets, int* __restrict__ cursor, int n)
{
    __shared__ int wsum[4];
    const int base = blockIdx.x * SCAN_TILE;
    const int tid  = threadIdx.x;
    const int lane = tid & 63;
    const int wid  = tid >> 6;
    int v[16], incl16 = 0;
    const int i0 = base + tid * 16;
    #pragma unroll
    for (int k = 0; k < 16; ++k) {
        v[k] = (i0 + k < n) ? deg[i0 + k] : 0;
        incl16 += v[k];
    }
    int tincl = incl16;
    #pragma unroll
    for (int off = 1; off < 64; off <<= 1) {
        int y = __shfl_up(tincl, off, 64);
        if (lane >= off) tincl += y;
    }
    if (lane == 63) wsum[wid] = tincl;
    __syncthreads();
    int woff = 0;
    #pragma unroll
    for (int w = 0; w < 4; ++w) woff += (w < wid) ? wsum[w] : 0;
    int run = texcl[blockIdx.x] + woff + (tincl - incl16);
    #pragma unroll
    for (int k = 0; k < 16; ++k) {
        if (i0 + k < n) { offsets[i0 + k] = run; cursor[i0 + k] = run; }
        run += v[k];
    }
}

__global__ void fill_kernel(const int* __restrict__ ei, int* __restrict__ cursor,
                            int2* __restrict__ epair, int E) {
    int e = blockIdx.x * 256 + threadIdx.x;
    if (e < E) {
        int d = ei[E + e];
        int s = ei[e];
        int slot = atomicAdd(&cursor[d], 1);
        epair[slot] = make_int2(e, s);
    }
}

// ---------------- gather / softmax / aggregate: wave per node, 4-edge ILP ----
__global__ __launch_bounds__(256) void agg_kernel(
    const int* __restrict__ offsets, const int2* __restrict__ epair,
    const uint16_t* __restrict__ kb, const uint16_t* __restrict__ vb,
    const uint16_t* __restrict__ qb, const uint16_t* __restrict__ tb,
    const float* __restrict__ skipf,
    const float* __restrict__ ea, const float* __restrict__ We,
    float* __restrict__ out, int n)
{
    const int i    = (int)((blockIdx.x * (unsigned)blockDim.x + threadIdx.x) >> 6);
    const int lane = threadIdx.x & 63;
    if (i >= n) return;
    const float qc = b2f(qb[(size_t)i * 64 + lane]);
    const float tc = b2f(tb[(size_t)i * 64 + lane]);
    const float sk = skipf[(size_t)i * 64 + lane];
    const int b0 = offsets[i], b1 = offsets[i + 1];

    float accv = 0.f, accg = 0.f, den = 0.f;
    for (int c0 = b0; c0 < b1; c0 += 64) {
        const int mcnt = min(64, b1 - c0);
        int2 ep = (c0 + lane < b1) ? epair[c0 + lane] : make_int2(0, 0);
        for (int jj = 0; jj < mcnt; jj += 4) {
            float pp[4], kv[4], vv[4], ev[4];
            #pragma unroll
            for (int u = 0; u < 4; ++u) {
                const bool act = (jj + u) < mcnt;       // wave-uniform
                const int lsel = act ? (jj + u) : jj;
                int eid = __shfl(ep.x, lsel, 64);
                int src = __shfl(ep.y, lsel, 64);
                kv[u] = b2f(kb[(size_t)src * 64 + lane]);
                vv[u] = b2f(vb[(size_t)src * 64 + lane]);
                ev[u] = ea[(size_t)eid * 64 + lane];
                pp[u] = act ? fmaf(qc, kv[u], tc * ev[u]) : -1e30f;
            }
            #pragma unroll
            for (int d2 = 32; d2 >= 1; d2 >>= 1) {
                #pragma unroll
                for (int u = 0; u < 4; ++u) pp[u] += __shfl_xor(pp[u], d2, 64);
            }
            #pragma unroll
            for (int u = 0; u < 4; ++u) {
                float ex = __expf(pp[u] * 0.125f);      // scale = 1/sqrt(64)
                den  += ex;
                accv  = fmaf(ex, vv[u], accv);
                accg  = fmaf(ex, ev[u], accg);
            }
        }
    }
    const float inv = 1.0f / (den + 1e-16f);
    const float g   = accg * inv;
    float o = fmaf(accv, inv, sk);
    #pragma unroll
    for (int r = 0; r < 64; ++r) {             // o += (g @ We)[lane]; We L1-hot
        float gr = __shfl(g, r, 64);
        o = fmaf(gr, We[r * 64 + lane], o);
    }
    out[(size_t)i * 64 + lane] = o;
}

extern "C" void kernel_launch(void* const* d_in, const int* in_sizes, int n_in,
                              void* d_out, int out_size, void* d_ws, size_t ws_size,
                              hipStream_t stream)
{
    const float* x   = (const float*)d_in[0];
    const int*   ei  = (const int*)d_in[1];
    const float* ea  = (const float*)d_in[2];
    const float* Wq  = (const float*)d_in[3];
    const float* bq  = (const float*)d_in[4];
    const float* Wk  = (const float*)d_in[5];
    const float* bk  = (const float*)d_in[6];
    const float* Wv  = (const float*)d_in[7];
    const float* bv  = (const float*)d_in[8];
    const float* We  = (const float*)d_in[9];
    const float* Wsk = (const float*)d_in[10];
    const float* bsk = (const float*)d_in[11];

    const int N = in_sizes[0] / 128;
    const int E = in_sizes[1] / 2;
    const int T = (N + SCAN_TILE - 1) / SCAN_TILE;   // 13 for N=50k (<=64 req'd)

    char* p = (char*)d_ws;
    auto alloc = [&](size_t bytes) {
        char* q = p; p += (bytes + 255) & ~(size_t)255; return q;
    };
    int*      deg     = (int*)alloc((size_t)N * 4);
    int*      cursor  = (int*)alloc((size_t)N * 4);
    int*      offsets = (int*)alloc((size_t)(N + 1) * 4);
    int*      tsum    = (int*)alloc((size_t)T * 4);
    int*      texcl   = (int*)alloc((size_t)T * 4);
    int2*     epair   = (int2*)alloc((size_t)E * 8);
    uint16_t* qb      = (uint16_t*)alloc((size_t)N * 64 * 2);
    uint16_t* kb      = (uint16_t*)alloc((size_t)N * 64 * 2);
    uint16_t* vb      = (uint16_t*)alloc((size_t)N * 64 * 2);
    uint16_t* tb      = (uint16_t*)alloc((size_t)N * 64 * 2);
    float*    skipf   = (float*)alloc((size_t)N * 64 * 4);

    hipMemsetAsync(deg, 0, (size_t)N * 4, stream);
    node_kernel<<<2048, 256, 0, stream>>>(x, Wq, bq, Wk, bk, Wv, bv, We, Wsk, bsk,
                                          qb, kb, vb, tb, skipf, N);
    hist_kernel<<<(E + 255) / 256, 256, 0, stream>>>(ei + E, deg, E);
    scan_reduce_kernel<<<T, 256, 0, stream>>>(deg, tsum, N);
    scan_tsum_kernel<<<1, 64, 0, stream>>>(tsum, texcl, offsets + N, T);
    scan_apply_kernel<<<T, 256, 0, stream>>>(deg, texcl, offsets, cursor, N);
    fill_kernel<<<(E + 255) / 256, 256, 0, stream>>>(ei, cursor, epair, E);
    agg_kernel<<<(N + 3) / 4, 256, 0, stream>>>(offsets, epair, kb, vb,
                                                qb, tb, skipf, ea, We,
                                                (float*)d_out, N);
}